// Round 1
// baseline (649.277 us; speedup 1.0000x reference)
//
#include <hip/hip_runtime.h>
#include <math.h>

#define T_   50
#define B_   2048
#define NS_  12
#define NC_  4
#define NSC_ 16
#define LDC  20          // padded LDS row stride for 16-wide matrices (bank decorrelation)
#define TAUS_STRIDE 808  // per-alpha stride for tau trajectories (50*16=800, +8 pad)

__device__ __forceinline__ float dot4f(const float4 a, const float4 b) {
    return a.x*b.x + a.y*b.y + a.z*b.z + a.w*b.w;
}
__device__ __forceinline__ void axpy4(float4& acc, float s, const float4 v) {
    acc.x += s*v.x; acc.y += s*v.y; acc.z += s*v.z; acc.w += s*v.w;
}

// ---------------------------------------------------------------------------
// Kernel 1: backward Riccati recursion. One 64-lane wave per batch element.
// Writes K (4x12 row-major) and kk (4) packed as 52 floats per (t,b) into ws.
// K/kk do not depend on u_nom -> computed ONCE for all 3 LQR iterations.
// ---------------------------------------------------------------------------
__global__ __launch_bounds__(64) void riccati_kernel(
    const float* __restrict__ Cg, const float* __restrict__ cg,
    const float* __restrict__ Fg, const float* __restrict__ fg,
    float* __restrict__ Kk)
{
    const int b    = blockIdx.x;
    const int lane = threadIdx.x;

    __shared__ __align__(16) float sV[144];      // V  12x12 (stride 12)
    __shared__ __align__(16) float sv[12];
    __shared__ __align__(16) float sF[12*LDC];   // F  12x16 (stride 20)
    __shared__ __align__(16) float sC[16*LDC];   // C  16x16 (stride 20)
    __shared__ __align__(16) float sc[16];
    __shared__ __align__(16) float sf[12];
    __shared__ __align__(16) float sP[12*LDC];   // P = V*F  12x16
    __shared__ __align__(16) float sQ[16*LDC];   // Q 16x16
    __shared__ __align__(16) float sq[16];
    __shared__ __align__(16) float stmp[12];     // V f + v
    __shared__ __align__(16) float sK[48];       // K 4x12 row-major
    __shared__ __align__(16) float skk[4];
    __shared__ __align__(16) float sM[144];      // M = K^T Qux  12x12 (stride 12)

    for (int i = lane; i < 144; i += 64) sV[i] = 0.f;
    if (lane < 12) sv[lane] = 0.f;
    __syncthreads();

    for (int t = T_ - 1; t >= 0; --t) {
        const size_t base = (size_t)t * B_ + b;

        // ---- stage C, F, c, f (coalesced float4) ----
        {
            const float4 v = ((const float4*)(Cg + base*256))[lane];
            const int row = lane >> 2, ch = (lane & 3) << 2;
            *(float4*)(sC + row*LDC + ch) = v;
        }
        if (lane < 48) {
            const float4 v = ((const float4*)(Fg + base*192))[lane];
            const int row = lane >> 2, ch = (lane & 3) << 2;
            *(float4*)(sF + row*LDC + ch) = v;
        } else if (lane < 52) {
            ((float4*)sc)[lane-48] = ((const float4*)(cg + base*16))[lane-48];
        } else if (lane < 55) {
            ((float4*)sf)[lane-52] = ((const float4*)(fg + base*12))[lane-52];
        }
        __syncthreads();

        // ---- P = V * F (12x16); tmp = V f + v ----
        if (lane < 48) {
            const int k = lane >> 2, jc = (lane & 3) << 2;
            float4 acc = make_float4(0.f,0.f,0.f,0.f);
            #pragma unroll
            for (int l = 0; l < 12; ++l) {
                axpy4(acc, sV[k*12 + l], *(const float4*)(sF + l*LDC + jc));
            }
            *(float4*)(sP + k*LDC + jc) = acc;
        } else if (lane < 60) {
            const int k = lane - 48;
            float acc = sv[k];
            #pragma unroll
            for (int l = 0; l < 12; ++l) acc += sV[k*12 + l] * sf[l];
            stmp[k] = acc;
        }
        __syncthreads();

        // ---- Q = C + F^T P (16x16); q = c + F^T tmp ----
        {
            const int i = lane >> 2, jc = (lane & 3) << 2;
            float4 acc = *(const float4*)(sC + i*LDC + jc);
            #pragma unroll
            for (int k = 0; k < 12; ++k) {
                axpy4(acc, sF[k*LDC + i], *(const float4*)(sP + k*LDC + jc));
            }
            *(float4*)(sQ + i*LDC + jc) = acc;
        }
        if (lane < 16) {
            float acc = sc[lane];
            #pragma unroll
            for (int k = 0; k < 12; ++k) acc += sF[k*LDC + lane] * stmp[k];
            sq[lane] = acc;
        }
        __syncthreads();

        // ---- solve Quu * sol = [Qux | qu]; K = -sol[:, :12], kk = -sol[:,12] ----
        {
            // Quu is SPD (Quu >= I): redundant 4x4 Cholesky in every lane.
            const float* Qu = sQ + 12*LDC + 12;
            const float a00=Qu[0],      a01=Qu[1],      a02=Qu[2],      a03=Qu[3];
            const float a11=Qu[LDC+1],  a12=Qu[LDC+2],  a13=Qu[LDC+3];
            const float a22=Qu[2*LDC+2],a23=Qu[2*LDC+3],a33=Qu[3*LDC+3];
            const float l00 = sqrtf(a00), i00 = 1.f/l00;
            const float l10 = a01*i00, l20 = a02*i00, l30 = a03*i00;
            const float l11 = sqrtf(a11 - l10*l10), i11 = 1.f/l11;
            const float l21 = (a12 - l20*l10)*i11;
            const float l31 = (a13 - l30*l10)*i11;
            const float l22 = sqrtf(a22 - l20*l20 - l21*l21), i22 = 1.f/l22;
            const float l32 = (a23 - l30*l20 - l31*l21)*i22;
            const float l33 = sqrtf(a33 - l30*l30 - l31*l31 - l32*l32), i33 = 1.f/l33;
            if (lane < 13) {   // one RHS column per lane
                float r0, r1, r2, r3;
                if (lane < 12) {
                    r0 = sQ[12*LDC + lane]; r1 = sQ[13*LDC + lane];
                    r2 = sQ[14*LDC + lane]; r3 = sQ[15*LDC + lane];
                } else {
                    r0 = sq[12]; r1 = sq[13]; r2 = sq[14]; r3 = sq[15];
                }
                const float y0 = r0*i00;
                const float y1 = (r1 - l10*y0)*i11;
                const float y2 = (r2 - l20*y0 - l21*y1)*i22;
                const float y3 = (r3 - l30*y0 - l31*y1 - l32*y2)*i33;
                const float z3 = y3*i33;
                const float z2 = (y2 - l32*z3)*i22;
                const float z1 = (y1 - l21*z2 - l31*z3)*i11;
                const float z0 = (y0 - l10*z1 - l20*z2 - l30*z3)*i00;
                if (lane < 12) {
                    sK[0*12+lane] = -z0; sK[1*12+lane] = -z1;
                    sK[2*12+lane] = -z2; sK[3*12+lane] = -z3;
                } else {
                    skk[0] = -z0; skk[1] = -z1; skk[2] = -z2; skk[3] = -z3;
                }
            }
        }
        __syncthreads();

        // ---- emit K,kk; M = K^T Qux; v' = qx + Qxu kk ----
        if (lane < 52) {
            (Kk + base*52)[lane] = (lane < 48) ? sK[lane] : skk[lane-48];
        }
        if (lane < 36) {
            const int i = lane / 3, jc = (lane % 3) << 2;
            float4 acc = make_float4(0.f,0.f,0.f,0.f);
            #pragma unroll
            for (int m = 0; m < 4; ++m) {
                axpy4(acc, sK[m*12 + i], *(const float4*)(sQ + (12+m)*LDC + jc));
            }
            *(float4*)(sM + i*12 + jc) = acc;
        } else if (lane < 48) {
            const int i = lane - 36;
            float acc = sq[i];
            #pragma unroll
            for (int m = 0; m < 4; ++m) acc += sQ[i*LDC + 12 + m] * skk[m];
            sv[i] = acc;   // v' (no readers of sv until next t's phase 1)
        }
        __syncthreads();

        // ---- V' = Qxx + 0.5(M + M^T)  (matches reference symmetrization) ----
        if (lane < 36) {
            const int i = lane / 3, jc = (lane % 3) << 2;
            const float4 q  = *(const float4*)(sQ + i*LDC + jc);
            const float4 m1 = *(const float4*)(sM + i*12 + jc);
            const float t0 = sM[(jc+0)*12 + i];
            const float t1 = sM[(jc+1)*12 + i];
            const float t2 = sM[(jc+2)*12 + i];
            const float t3 = sM[(jc+3)*12 + i];
            float4 r;
            r.x = q.x + 0.5f*(m1.x + t0);
            r.y = q.y + 0.5f*(m1.y + t1);
            r.z = q.z + 0.5f*(m1.z + t2);
            r.w = q.w + 0.5f*(m1.w + t3);
            *(float4*)(sV + i*12 + jc) = r;
        }
        __syncthreads();
    }
}

// ---------------------------------------------------------------------------
// Kernel 2: 3 LQR iterations of 5-alpha forward rollout + line-search select.
// One 64-lane wave per batch element; tau trajectories for all 5 alphas in LDS.
// ---------------------------------------------------------------------------
__global__ __launch_bounds__(64) void rollout_kernel(
    const float* __restrict__ x0g, const float* __restrict__ Cg,
    const float* __restrict__ cg,  const float* __restrict__ Fg,
    const float* __restrict__ fg,  const float* __restrict__ Kk,
    float* __restrict__ outg)
{
    const int b    = blockIdx.x;
    const int lane = threadIdx.x;

    __shared__ __align__(16) float staus[5*TAUS_STRIDE]; // [a][t][16], a-stride 808
    __shared__ __align__(16) float sunom[T_*NC_];        // [t][4]
    __shared__ __align__(16) float sx[5*12];             // current x per alpha
    __shared__ __align__(16) float sx0[12];
    __shared__ __align__(16) float sC[16*LDC];
    __shared__ __align__(16) float sF[12*LDC];
    __shared__ __align__(16) float sKk[52];
    __shared__ __align__(16) float sc[16];
    __shared__ __align__(16) float sf[12];
    __shared__ float scost[5];
    __shared__ int   sbest;

    for (int i = lane; i < T_*NC_; i += 64) sunom[i] = 0.f;
    if (lane < 3) ((float4*)sx0)[lane] = ((const float4*)(x0g + b*12))[lane];
    __syncthreads();

    for (int iter = 0; iter < 3; ++iter) {
        if (lane < 60) sx[lane] = sx0[lane % 12];
        float ca = 0.f;   // cost accumulator for alpha = lane>>4 (0..3)
        float cb = 0.f;   // cost accumulator for alpha 4 (lanes 0..15)
        __syncthreads();

        for (int t = 0; t < T_; ++t) {
            const size_t base = (size_t)t * B_ + b;

            // ---- stage C, F, K|kk, c, f ----
            {
                const float4 v = ((const float4*)(Cg + base*256))[lane];
                const int row = lane >> 2, ch = (lane & 3) << 2;
                *(float4*)(sC + row*LDC + ch) = v;
            }
            if (lane < 48) {
                const float4 v = ((const float4*)(Fg + base*192))[lane];
                const int row = lane >> 2, ch = (lane & 3) << 2;
                *(float4*)(sF + row*LDC + ch) = v;
            } else if (lane < 61) {
                ((float4*)sKk)[lane-48] = ((const float4*)(Kk + base*52))[lane-48];
            }
            if (lane < 4) {
                ((float4*)sc)[lane] = ((const float4*)(cg + base*16))[lane];
            } else if (lane < 7) {
                ((float4*)sf)[lane-4] = ((const float4*)(fg + base*12))[lane-4];
            }
            __syncthreads();

            // ---- phase A: u per (alpha, i); copy x into tau slots ----
            if (lane < 20) {
                const int a = lane >> 2, i = lane & 3;
                const float* Kr = sKk + i*12;
                const float* xa = sx  + a*12;
                float ulqr = dot4f(*(const float4*)(Kr  ), *(const float4*)(xa  ))
                           + dot4f(*(const float4*)(Kr+4), *(const float4*)(xa+4))
                           + dot4f(*(const float4*)(Kr+8), *(const float4*)(xa+8))
                           + sKk[48 + i];
                const float al = ldexpf(1.0f, -a);   // 0.5^a
                float u = (1.f - al) * sunom[t*4 + i] + al * ulqr;
                u = fminf(1.f, fmaxf(-1.f, u));
                staus[a*TAUS_STRIDE + t*16 + 12 + i] = u;
            } else if (lane >= 32 && lane < 47) {
                const int idx = lane - 32;
                const int a = idx / 3, ch = (idx % 3) << 2;
                *(float4*)(staus + a*TAUS_STRIDE + t*16 + ch) =
                    *(const float4*)(sx + a*12 + ch);
            }
            __syncthreads();

            // ---- phase B: cost term per (alpha, i) ----
            {
                const int a = lane >> 4, i = lane & 15;
                const float* tau = staus + a*TAUS_STRIDE + t*16;
                const float* Cr  = sC + i*LDC;
                float acc = 0.f;
                #pragma unroll
                for (int chv = 0; chv < 4; ++chv) {
                    acc += dot4f(*(const float4*)(Cr + 4*chv),
                                 *(const float4*)(tau + 4*chv));
                }
                ca += (0.5f*acc + sc[i]) * tau[i];
            }
            if (lane < 16) {
                const int i = lane;
                const float* tau = staus + 4*TAUS_STRIDE + t*16;
                const float* Cr  = sC + i*LDC;
                float acc = 0.f;
                #pragma unroll
                for (int chv = 0; chv < 4; ++chv) {
                    acc += dot4f(*(const float4*)(Cr + 4*chv),
                                 *(const float4*)(tau + 4*chv));
                }
                cb += (0.5f*acc + sc[i]) * tau[i];
            }

            // ---- phase C: x_next per (alpha, i) ----
            if (lane < 60) {
                const int a = lane / 12, i = lane - a*12;
                const float* tau = staus + a*TAUS_STRIDE + t*16;
                const float* Fr  = sF + i*LDC;
                float acc = sf[i];
                #pragma unroll
                for (int chv = 0; chv < 4; ++chv) {
                    acc += dot4f(*(const float4*)(Fr + 4*chv),
                                 *(const float4*)(tau + 4*chv));
                }
                sx[a*12 + i] = acc;   // no reader of sx until after barrier
            }
            __syncthreads();
        } // t

        // ---- reduce costs (16-lane groups), select best alpha ----
        #pragma unroll
        for (int off = 1; off < 16; off <<= 1) {
            ca += __shfl_xor(ca, off, 16);
            cb += __shfl_xor(cb, off, 16);
        }
        if ((lane & 15) == 0) scost[lane >> 4] = ca;
        if (lane == 0) scost[4] = cb;
        __syncthreads();
        if (lane == 0) {
            int bi = 0; float bc = scost[0];
            #pragma unroll
            for (int a = 1; a < 5; ++a) {
                if (scost[a] < bc) { bc = scost[a]; bi = a; }  // first-min: matches jnp.argmin
            }
            sbest = bi;
        }
        __syncthreads();
        const int best = sbest;

        // ---- u_nom <- best trajectory's u; final iter: write taus out ----
        for (int idx = lane; idx < T_*NC_; idx += 64) {
            const int tt = idx >> 2, i = idx & 3;
            sunom[idx] = staus[best*TAUS_STRIDE + tt*16 + 12 + i];
        }
        if (iter == 2) {
            for (int idx = lane; idx < T_*NSC_; idx += 64) {
                const int tt = idx >> 4, j = idx & 15;
                outg[((size_t)tt*B_ + b)*16 + j] = staus[best*TAUS_STRIDE + tt*16 + j];
            }
        }
        __syncthreads();
    } // iter
}

extern "C" void kernel_launch(void* const* d_in, const int* in_sizes, int n_in,
                              void* d_out, int out_size, void* d_ws, size_t ws_size,
                              hipStream_t stream) {
    const float* x0 = (const float*)d_in[0];
    const float* C  = (const float*)d_in[1];
    const float* c  = (const float*)d_in[2];
    const float* F  = (const float*)d_in[3];
    const float* f  = (const float*)d_in[4];
    float* out = (float*)d_out;
    float* Kk  = (float*)d_ws;   // needs 50*2048*52*4 = 21.3 MB

    riccati_kernel<<<B_, 64, 0, stream>>>(C, c, F, f, Kk);
    rollout_kernel<<<B_, 64, 0, stream>>>(x0, C, c, F, f, Kk, out);
}

// Round 2
// 427.782 us; speedup vs baseline: 1.5178x; 1.5178x over previous
//
#include <hip/hip_runtime.h>
#include <math.h>

#define T_   50
#define B_   2048
#define NS_  12
#define NC_  4
#define NSC_ 16
#define LDC  20          // padded LDS row stride for 16-wide matrices (bank decorrelation)
#define TAUS_STRIDE 808  // per-alpha stride for tau trajectories (50*16=800, +8 pad)

__device__ __forceinline__ float dot4f(const float4 a, const float4 b) {
    return a.x*b.x + a.y*b.y + a.z*b.z + a.w*b.w;
}
__device__ __forceinline__ void axpy4(float4& acc, float s, const float4 v) {
    acc.x += s*v.x; acc.y += s*v.y; acc.z += s*v.z; acc.w += s*v.w;
}

// Wave-local sync for single-wave (64-thread) blocks. Orders LDS traffic
// (s_waitcnt lgkmcnt(0)) WITHOUT draining vmcnt, so prefetched global loads
// stay in flight across compute phases. __syncthreads() would emit
// s_waitcnt vmcnt(0) lgkmcnt(0) + s_barrier and kill the pipeline.
// 0xC07F = vmcnt(63) expcnt(7) lgkmcnt(0) in gfx9-lineage encoding.
__device__ __forceinline__ void wsync() {
    __builtin_amdgcn_wave_barrier();
    __builtin_amdgcn_s_waitcnt(0xC07F);
    __builtin_amdgcn_wave_barrier();
}

// ---------------------------------------------------------------------------
// Kernel 1: backward Riccati recursion. One 64-lane wave per batch element.
// Register-prefetches (C,F,c,f) for step t-1 while computing step t.
// ---------------------------------------------------------------------------
struct RicPref { float4 rC, rAux; };

__device__ __forceinline__ RicPref ric_load(
    const float* Cg, const float* cg, const float* Fg, const float* fg,
    int t, int b, int lane)
{
    RicPref p;
    const size_t base = (size_t)t * B_ + b;
    p.rC = ((const float4*)(Cg + base*256))[lane];
    if (lane < 48)      p.rAux = ((const float4*)(Fg + base*192))[lane];
    else if (lane < 52) p.rAux = ((const float4*)(cg + base*16))[lane-48];
    else if (lane < 55) p.rAux = ((const float4*)(fg + base*12))[lane-52];
    return p;
}

__global__ __launch_bounds__(64) void riccati_kernel(
    const float* __restrict__ Cg, const float* __restrict__ cg,
    const float* __restrict__ Fg, const float* __restrict__ fg,
    float* __restrict__ Kk)
{
    const int b    = blockIdx.x;
    const int lane = threadIdx.x;

    __shared__ __align__(16) float sV[144];      // V  12x12 (stride 12)
    __shared__ __align__(16) float sv[12];
    __shared__ __align__(16) float sF[12*LDC];   // F  12x16 (stride 20)
    __shared__ __align__(16) float sC[16*LDC];   // C  16x16 (stride 20)
    __shared__ __align__(16) float sc[16];
    __shared__ __align__(16) float sf[12];
    __shared__ __align__(16) float sP[12*LDC];   // P = V*F  12x16
    __shared__ __align__(16) float sQ[16*LDC];   // Q 16x16
    __shared__ __align__(16) float sq[16];
    __shared__ __align__(16) float stmp[12];     // V f + v
    __shared__ __align__(16) float sK[48];       // K 4x12 row-major
    __shared__ __align__(16) float skk[4];
    __shared__ __align__(16) float sM[144];      // M = K^T Qux  12x12 (stride 12)

    for (int i = lane; i < 144; i += 64) sV[i] = 0.f;
    if (lane < 12) sv[lane] = 0.f;

    RicPref cur = ric_load(Cg, cg, Fg, fg, T_-1, b, lane);
    wsync();

    for (int t = T_ - 1; t >= 0; --t) {
        const size_t base = (size_t)t * B_ + b;

        // ---- stage current step's data from prefetch registers ----
        wsync();   // WAR: prior phases' LDS reads complete before overwrite
        {
            const int row = lane >> 2, ch = (lane & 3) << 2;
            *(float4*)(sC + row*LDC + ch) = cur.rC;
            if (lane < 48)      *(float4*)(sF + row*LDC + ch) = cur.rAux;
            else if (lane < 52) ((float4*)sc)[lane-48] = cur.rAux;
            else if (lane < 55) ((float4*)sf)[lane-52] = cur.rAux;
        }
        RicPref nxt = ric_load(Cg, cg, Fg, fg, (t > 0) ? t-1 : 0, b, lane);
        wsync();

        // ---- P = V * F (12x16); tmp = V f + v ----
        if (lane < 48) {
            const int k = lane >> 2, jc = (lane & 3) << 2;
            float4 acc = make_float4(0.f,0.f,0.f,0.f);
            #pragma unroll
            for (int l = 0; l < 12; ++l) {
                axpy4(acc, sV[k*12 + l], *(const float4*)(sF + l*LDC + jc));
            }
            *(float4*)(sP + k*LDC + jc) = acc;
        } else if (lane < 60) {
            const int k = lane - 48;
            float acc = sv[k];
            #pragma unroll
            for (int l = 0; l < 12; ++l) acc += sV[k*12 + l] * sf[l];
            stmp[k] = acc;
        }
        wsync();

        // ---- Q = C + F^T P (16x16); q = c + F^T tmp ----
        {
            const int i = lane >> 2, jc = (lane & 3) << 2;
            float4 acc = *(const float4*)(sC + i*LDC + jc);
            #pragma unroll
            for (int k = 0; k < 12; ++k) {
                axpy4(acc, sF[k*LDC + i], *(const float4*)(sP + k*LDC + jc));
            }
            *(float4*)(sQ + i*LDC + jc) = acc;
        }
        if (lane < 16) {
            float acc = sc[lane];
            #pragma unroll
            for (int k = 0; k < 12; ++k) acc += sF[k*LDC + lane] * stmp[k];
            sq[lane] = acc;
        }
        wsync();

        // ---- solve Quu * sol = [Qux | qu]; K = -sol[:, :12], kk = -sol[:,12] ----
        {
            // Quu is SPD (Quu >= I): redundant 4x4 Cholesky in every lane.
            const float* Qu = sQ + 12*LDC + 12;
            const float a00=Qu[0],      a01=Qu[1],      a02=Qu[2],      a03=Qu[3];
            const float a11=Qu[LDC+1],  a12=Qu[LDC+2],  a13=Qu[LDC+3];
            const float a22=Qu[2*LDC+2],a23=Qu[2*LDC+3],a33=Qu[3*LDC+3];
            const float l00 = sqrtf(a00), i00 = 1.f/l00;
            const float l10 = a01*i00, l20 = a02*i00, l30 = a03*i00;
            const float l11 = sqrtf(a11 - l10*l10), i11 = 1.f/l11;
            const float l21 = (a12 - l20*l10)*i11;
            const float l31 = (a13 - l30*l10)*i11;
            const float l22 = sqrtf(a22 - l20*l20 - l21*l21), i22 = 1.f/l22;
            const float l32 = (a23 - l30*l20 - l31*l21)*i22;
            const float l33 = sqrtf(a33 - l30*l30 - l31*l31 - l32*l32), i33 = 1.f/l33;
            if (lane < 13) {   // one RHS column per lane
                float r0, r1, r2, r3;
                if (lane < 12) {
                    r0 = sQ[12*LDC + lane]; r1 = sQ[13*LDC + lane];
                    r2 = sQ[14*LDC + lane]; r3 = sQ[15*LDC + lane];
                } else {
                    r0 = sq[12]; r1 = sq[13]; r2 = sq[14]; r3 = sq[15];
                }
                const float y0 = r0*i00;
                const float y1 = (r1 - l10*y0)*i11;
                const float y2 = (r2 - l20*y0 - l21*y1)*i22;
                const float y3 = (r3 - l30*y0 - l31*y1 - l32*y2)*i33;
                const float z3 = y3*i33;
                const float z2 = (y2 - l32*z3)*i22;
                const float z1 = (y1 - l21*z2 - l31*z3)*i11;
                const float z0 = (y0 - l10*z1 - l20*z2 - l30*z3)*i00;
                if (lane < 12) {
                    sK[0*12+lane] = -z0; sK[1*12+lane] = -z1;
                    sK[2*12+lane] = -z2; sK[3*12+lane] = -z3;
                } else {
                    skk[0] = -z0; skk[1] = -z1; skk[2] = -z2; skk[3] = -z3;
                }
            }
        }
        wsync();

        // ---- emit K,kk; M = K^T Qux; v' = qx + Qxu kk ----
        if (lane < 52) {
            (Kk + base*52)[lane] = (lane < 48) ? sK[lane] : skk[lane-48];
        }
        if (lane < 36) {
            const int i = lane / 3, jc = (lane % 3) << 2;
            float4 acc = make_float4(0.f,0.f,0.f,0.f);
            #pragma unroll
            for (int m = 0; m < 4; ++m) {
                axpy4(acc, sK[m*12 + i], *(const float4*)(sQ + (12+m)*LDC + jc));
            }
            *(float4*)(sM + i*12 + jc) = acc;
        } else if (lane < 48) {
            const int i = lane - 36;
            float acc = sq[i];
            #pragma unroll
            for (int m = 0; m < 4; ++m) acc += sQ[i*LDC + 12 + m] * skk[m];
            sv[i] = acc;   // v' (no readers of sv until next t's phase 1)
        }
        wsync();

        // ---- V' = Qxx + 0.5(M + M^T)  (matches reference symmetrization) ----
        if (lane < 36) {
            const int i = lane / 3, jc = (lane % 3) << 2;
            const float4 q  = *(const float4*)(sQ + i*LDC + jc);
            const float4 m1 = *(const float4*)(sM + i*12 + jc);
            const float t0 = sM[(jc+0)*12 + i];
            const float t1 = sM[(jc+1)*12 + i];
            const float t2 = sM[(jc+2)*12 + i];
            const float t3 = sM[(jc+3)*12 + i];
            float4 r;
            r.x = q.x + 0.5f*(m1.x + t0);
            r.y = q.y + 0.5f*(m1.y + t1);
            r.z = q.z + 0.5f*(m1.z + t2);
            r.w = q.w + 0.5f*(m1.w + t3);
            *(float4*)(sV + i*12 + jc) = r;
        }
        cur = nxt;
        // loop-top wsync orders V' writes vs next step's P reads
    }
}

// ---------------------------------------------------------------------------
// Kernel 2: 3 LQR iterations of 5-alpha forward rollout + line-search select.
// One 64-lane wave per batch element; register prefetch of step t+1.
// ---------------------------------------------------------------------------
struct RollPref { float4 rC, rAux, rcf; };

__device__ __forceinline__ RollPref roll_load(
    const float* Cg, const float* cg, const float* Fg, const float* fg,
    const float* Kk, int t, int b, int lane)
{
    RollPref p;
    const size_t base = (size_t)t * B_ + b;
    p.rC = ((const float4*)(Cg + base*256))[lane];
    if (lane < 48)      p.rAux = ((const float4*)(Fg + base*192))[lane];
    else if (lane < 61) p.rAux = ((const float4*)(Kk + base*52))[lane-48];
    if (lane < 4)       p.rcf = ((const float4*)(cg + base*16))[lane];
    else if (lane < 7)  p.rcf = ((const float4*)(fg + base*12))[lane-4];
    return p;
}

__global__ __launch_bounds__(64) void rollout_kernel(
    const float* __restrict__ x0g, const float* __restrict__ Cg,
    const float* __restrict__ cg,  const float* __restrict__ Fg,
    const float* __restrict__ fg,  const float* __restrict__ Kk,
    float* __restrict__ outg)
{
    const int b    = blockIdx.x;
    const int lane = threadIdx.x;

    __shared__ __align__(16) float staus[5*TAUS_STRIDE]; // [a][t][16], a-stride 808
    __shared__ __align__(16) float sunom[T_*NC_];        // [t][4]
    __shared__ __align__(16) float sx[5*12];             // current x per alpha
    __shared__ __align__(16) float sx0[12];
    __shared__ __align__(16) float sC[16*LDC];
    __shared__ __align__(16) float sF[12*LDC];
    __shared__ __align__(16) float sKk[56];
    __shared__ __align__(16) float sc[16];
    __shared__ __align__(16) float sf[12];
    __shared__ float scost[5];
    __shared__ int   sbest;

    for (int i = lane; i < T_*NC_; i += 64) sunom[i] = 0.f;
    if (lane < 3) ((float4*)sx0)[lane] = ((const float4*)(x0g + b*12))[lane];

    RollPref cur = roll_load(Cg, cg, Fg, fg, Kk, 0, b, lane);
    wsync();

    for (int iter = 0; iter < 3; ++iter) {
        if (lane < 60) sx[lane] = sx0[lane % 12];
        float ca = 0.f;   // cost accumulator for alpha = lane>>4 (0..3)
        float cb = 0.f;   // cost accumulator for alpha 4 (lanes 0..15)
        wsync();

        for (int t = 0; t < T_; ++t) {
            // ---- stage step-t data from prefetch registers ----
            wsync();   // WAR: prior phases' LDS reads complete before overwrite
            {
                const int row = lane >> 2, ch = (lane & 3) << 2;
                *(float4*)(sC + row*LDC + ch) = cur.rC;
                if (lane < 48)      *(float4*)(sF + row*LDC + ch) = cur.rAux;
                else if (lane < 61) ((float4*)sKk)[lane-48] = cur.rAux;
                if (lane < 4)       ((float4*)sc)[lane]   = cur.rcf;
                else if (lane < 7)  ((float4*)sf)[lane-4] = cur.rcf;
            }
            // prefetch t+1 (wraps to 0: exactly what the next iter needs)
            RollPref nxt = roll_load(Cg, cg, Fg, fg, Kk,
                                     (t+1 < T_) ? t+1 : 0, b, lane);
            wsync();

            // ---- phase A: u per (alpha, i); copy x into tau slots ----
            if (lane < 20) {
                const int a = lane >> 2, i = lane & 3;
                const float* Kr = sKk + i*12;
                const float* xa = sx  + a*12;
                float ulqr = dot4f(*(const float4*)(Kr  ), *(const float4*)(xa  ))
                           + dot4f(*(const float4*)(Kr+4), *(const float4*)(xa+4))
                           + dot4f(*(const float4*)(Kr+8), *(const float4*)(xa+8))
                           + sKk[48 + i];
                const float al = ldexpf(1.0f, -a);   // 0.5^a
                float u = (1.f - al) * sunom[t*4 + i] + al * ulqr;
                u = fminf(1.f, fmaxf(-1.f, u));
                staus[a*TAUS_STRIDE + t*16 + 12 + i] = u;
            } else if (lane >= 32 && lane < 47) {
                const int idx = lane - 32;
                const int a = idx / 3, ch = (idx % 3) << 2;
                *(float4*)(staus + a*TAUS_STRIDE + t*16 + ch) =
                    *(const float4*)(sx + a*12 + ch);
            }
            wsync();

            // ---- phase B: cost term per (alpha, i) ----
            {
                const int a = lane >> 4, i = lane & 15;
                const float* tau = staus + a*TAUS_STRIDE + t*16;
                const float* Cr  = sC + i*LDC;
                float acc = 0.f;
                #pragma unroll
                for (int chv = 0; chv < 4; ++chv) {
                    acc += dot4f(*(const float4*)(Cr + 4*chv),
                                 *(const float4*)(tau + 4*chv));
                }
                ca += (0.5f*acc + sc[i]) * tau[i];
            }
            if (lane < 16) {
                const int i = lane;
                const float* tau = staus + 4*TAUS_STRIDE + t*16;
                const float* Cr  = sC + i*LDC;
                float acc = 0.f;
                #pragma unroll
                for (int chv = 0; chv < 4; ++chv) {
                    acc += dot4f(*(const float4*)(Cr + 4*chv),
                                 *(const float4*)(tau + 4*chv));
                }
                cb += (0.5f*acc + sc[i]) * tau[i];
            }

            // ---- phase C: x_next per (alpha, i) ----
            if (lane < 60) {
                const int a = lane / 12, i = lane - a*12;
                const float* tau = staus + a*TAUS_STRIDE + t*16;
                const float* Fr  = sF + i*LDC;
                float acc = sf[i];
                #pragma unroll
                for (int chv = 0; chv < 4; ++chv) {
                    acc += dot4f(*(const float4*)(Fr + 4*chv),
                                 *(const float4*)(tau + 4*chv));
                }
                sx[a*12 + i] = acc;   // loop-top wsync orders vs next phase A
            }
            cur = nxt;
        } // t

        // ---- reduce costs (16-lane groups), select best alpha ----
        #pragma unroll
        for (int off = 1; off < 16; off <<= 1) {
            ca += __shfl_xor(ca, off, 16);
            cb += __shfl_xor(cb, off, 16);
        }
        if ((lane & 15) == 0) scost[lane >> 4] = ca;
        if (lane == 0) scost[4] = cb;
        wsync();
        if (lane == 0) {
            int bi = 0; float bc = scost[0];
            #pragma unroll
            for (int a = 1; a < 5; ++a) {
                if (scost[a] < bc) { bc = scost[a]; bi = a; }  // first-min: matches jnp.argmin
            }
            sbest = bi;
        }
        wsync();
        const int best = sbest;

        // ---- u_nom <- best trajectory's u; final iter: write taus out ----
        for (int idx = lane; idx < T_*NC_; idx += 64) {
            const int tt = idx >> 2, i = idx & 3;
            sunom[idx] = staus[best*TAUS_STRIDE + tt*16 + 12 + i];
        }
        if (iter == 2) {
            for (int idx = lane; idx < T_*NSC_; idx += 64) {
                const int tt = idx >> 4, j = idx & 15;
                outg[((size_t)tt*B_ + b)*16 + j] = staus[best*TAUS_STRIDE + tt*16 + j];
            }
        }
        wsync();
    } // iter
}

extern "C" void kernel_launch(void* const* d_in, const int* in_sizes, int n_in,
                              void* d_out, int out_size, void* d_ws, size_t ws_size,
                              hipStream_t stream) {
    const float* x0 = (const float*)d_in[0];
    const float* C  = (const float*)d_in[1];
    const float* c  = (const float*)d_in[2];
    const float* F  = (const float*)d_in[3];
    const float* f  = (const float*)d_in[4];
    float* out = (float*)d_out;
    float* Kk  = (float*)d_ws;   // needs 50*2048*52*4 = 21.3 MB

    riccati_kernel<<<B_, 64, 0, stream>>>(C, c, F, f, Kk);
    rollout_kernel<<<B_, 64, 0, stream>>>(x0, C, c, F, f, Kk, out);
}